// Round 4
// baseline (176.603 us; speedup 1.0000x reference)
//
#include <hip/hip_runtime.h>

// Problem constants
constexpr int   FRAMES   = 128 * 1024;   // B*T = 131072
constexpr int   NB       = 50;           // bones (== joints)
constexpr int   FRAME_F  = 150;          // floats per frame
// final = 0.1 * (sum_abs + 0.1*sum_sq) / (FRAMES*150)
constexpr float SCALE    = 0.1f / (float)(FRAMES * FRAME_F);

constexpr int FPW    = 16;                    // frames per wave
constexpr int NWAVES = FRAMES / FPW;          // 8192 waves
constexpr int BLOCK  = 256;                   // 4 waves/block
constexpr int NBLK   = NWAVES * 64 / BLOCK;   // 2048 blocks

__global__ __launch_bounds__(256) void bone_loss_main(
    const float* __restrict__ preds,
    const float* __restrict__ targets,
    float* __restrict__ partials)
{
    const int gid   = blockIdx.x * BLOCK + threadIdx.x;
    const int wave  = gid >> 6;
    const int lane  = threadIdx.x & 63;
    const bool act  = lane < NB;
    const int  jcl  = act ? lane : (NB - 1);          // clamp inactive lanes
    const int  sidx = (lane >= NB - 1) ? lane - (NB - 1) : lane + 1;  // (lane+1)%50

    const long fbase = (long)wave * FPW;
    const float* pp = preds   + fbase * FRAME_F + jcl * 3;
    const float* tp = targets + fbase * FRAME_F + jcl * 3;

    // ---- phase 1: issue ALL loads (32 x dwordx3 = 19.2 KB/wave in flight) ----
    float P[FPW][3], T[FPW][3];
    #pragma unroll
    for (int i = 0; i < FPW; ++i) {
        const float* a = pp + i * FRAME_F;
        const float* b = tp + i * FRAME_F;
        P[i][0] = a[0]; P[i][1] = a[1]; P[i][2] = a[2];
        T[i][0] = b[0]; T[i][1] = b[1]; T[i][2] = b[2];
    }

    // ---- phase 2: compute (fine-grained vmcnt lets frame 0 start early) ----
    float acc = 0.0f;
    #pragma unroll
    for (int i = 0; i < FPW; ++i) {
        const float p0 = P[i][0], p1 = P[i][1], p2 = P[i][2];
        const float t0 = T[i][0], t1 = T[i][1], t2 = T[i][2];

        // masks: targets*mask == targets identically; mask preds only
        const float m0 = (t0 != 0.0f) ? 1.0f : 0.0f;
        const float m1 = (t1 != 0.0f) ? 1.0f : 0.0f;
        const float m2 = (t2 != 0.0f) ? 1.0f : 0.0f;
        const float pm0 = p0 * m0, pm1 = p1 * m1, pm2 = p2 * m2;

        // L1 term over this lane's owned joint
        const float ab = fabsf(pm0 - t0) + fabsf(pm1 - t1) + fabsf(pm2 - t2);

        // neighbor joint via cross-lane: neighbor's masked-pred IS qm, raw t IS u
        const float qm0 = __shfl(pm0, sidx, 64);
        const float qm1 = __shfl(pm1, sidx, 64);
        const float qm2 = __shfl(pm2, sidx, 64);
        const float u0  = __shfl(t0,  sidx, 64);
        const float u1  = __shfl(t1,  sidx, 64);
        const float u2  = __shfl(t2,  sidx, 64);

        const float pd0 = pm0 - qm0, pd1 = pm1 - qm1, pd2 = pm2 - qm2;
        const float td0 = t0  - u0,  td1 = t1  - u1,  td2 = t2  - u2;

        const float pl2 = pd0*pd0 + pd1*pd1 + pd2*pd2;
        const float tl2 = td0*td0 + td1*td1 + td2*td2;
        // 1/(len+tiny): rsq approx (rel err ~1e-7, irrelevant to a mean), zero-guarded
        const float pri = (pl2 > 0.0f) ? __builtin_amdgcn_rsqf(pl2) : 0.0f;
        const float tri = (tl2 > 0.0f) ? __builtin_amdgcn_rsqf(tl2) : 0.0f;

        const float d0 = pd0 * pri - td0 * tri;
        const float d1 = pd1 * pri - td1 * tri;
        const float d2 = pd2 * pri - td2 * tri;
        const float sq = m0*d0*d0 + m1*d1*d1 + m2*d2*d2;   // re-mask ([:150] slice)

        acc += act ? (ab + 0.1f * sq) : 0.0f;
    }

    // ---- block reduction ----
    #pragma unroll
    for (int off = 32; off > 0; off >>= 1)
        acc += __shfl_down(acc, off, 64);

    __shared__ float ws[4];
    const int wid = threadIdx.x >> 6;
    if ((threadIdx.x & 63) == 0) ws[wid] = acc;
    __syncthreads();
    if (threadIdx.x == 0)
        partials[blockIdx.x] = ws[0] + ws[1] + ws[2] + ws[3];
}

__global__ __launch_bounds__(256) void bone_loss_finish(
    const float* __restrict__ partials,
    float* __restrict__ out)
{
    float v = 0.0f;
    for (int i = threadIdx.x; i < NBLK; i += 256)
        v += partials[i];

    #pragma unroll
    for (int off = 32; off > 0; off >>= 1)
        v += __shfl_down(v, off, 64);

    __shared__ float ws[4];
    const int wid = threadIdx.x >> 6;
    if ((threadIdx.x & 63) == 0) ws[wid] = v;
    __syncthreads();
    if (threadIdx.x == 0)
        out[0] = (ws[0] + ws[1] + ws[2] + ws[3]) * SCALE;
}

extern "C" void kernel_launch(void* const* d_in, const int* in_sizes, int n_in,
                              void* d_out, int out_size, void* d_ws, size_t ws_size,
                              hipStream_t stream) {
    const float* preds   = (const float*)d_in[0];
    const float* targets = (const float*)d_in[1];
    float* out      = (float*)d_out;
    float* partials = (float*)d_ws;       // NBLK floats = 8 KB

    bone_loss_main<<<NBLK, BLOCK, 0, stream>>>(preds, targets, partials);
    bone_loss_finish<<<1, 256, 0, stream>>>(partials, out);
}